// Round 8
// baseline (402.451 us; speedup 1.0000x reference)
//
#include <hip/hip_runtime.h>

#define NUM_USERS 100000
#define NUM_ITEMS 50000
#define NUM_OTHERS 20000
#define N_NODES 170000   // NUM_USERS + NUM_ITEMS + NUM_OTHERS (= 4*42500, even)
#define DIM 64
#define NNZ 5000000
#define BATCH 8192

#define BSHIFT 10
#define RPB (1 << BSHIFT)                       // 1024 rows per bucket
#define NBUCK ((N_NODES + RPB - 1) / RPB)       // 167 buckets
#define COLMASK 0x3FFFF                         // 18 bits for col (N_NODES < 2^18)
#define PADSLACK (31 * RPB)                     // max pad overhead per bucket (pad-to-32)
#define NBLK 512                                // blocks for scatter pass
#define CHUNK ((NNZ + NBLK - 1) / NBLK)         // 9766 edges per block
#define HBLK 1024                               // blocks for hist pass
#define HCHUNK ((NNZ + HBLK - 1) / HBLK)

typedef float f32x2 __attribute__((ext_vector_type(2)));

// fp32 -> bf16 round-to-nearest-even
static __device__ __forceinline__ unsigned f2bf(float f) {
    unsigned u = __float_as_uint(f);
    u = (u + 0x7fff + ((u >> 16) & 1)) >> 16;
    return u;
}
static __device__ __forceinline__ float bflo(unsigned u) {   // low ushort -> f32
    return __uint_as_float(u << 16);
}
static __device__ __forceinline__ float bfhi(unsigned u) {   // high ushort -> f32
    return __uint_as_float(u & 0xFFFF0000u);
}

// ---------------------------------------------------------------------------
// cur0 = concat(user_emb, item_emb, other_emb)  -> bf16
// ---------------------------------------------------------------------------
__global__ void build_cur0(const float* __restrict__ ue,
                           const float* __restrict__ ie,
                           const float* __restrict__ oe,
                           ushort4* __restrict__ cur) {
    const int total = N_NODES * (DIM / 4);
    for (int i = blockIdx.x * blockDim.x + threadIdx.x; i < total;
         i += gridDim.x * blockDim.x) {
        const int node = i >> 4;
        const int sub  = i & 15;
        const float* src;
        if (node < NUM_USERS)                  src = ue + (size_t)node * DIM;
        else if (node < NUM_USERS + NUM_ITEMS) src = ie + (size_t)(node - NUM_USERS) * DIM;
        else                                   src = oe + (size_t)(node - NUM_USERS - NUM_ITEMS) * DIM;
        const float4 f = reinterpret_cast<const float4*>(src)[sub];
        ushort4 o;
        o.x = (unsigned short)f2bf(f.x); o.y = (unsigned short)f2bf(f.y);
        o.z = (unsigned short)f2bf(f.z); o.w = (unsigned short)f2bf(f.w);
        cur[i] = o;
    }
}

// ---------------------------------------------------------------------------
// batch accumulators start as layer-0 embeddings (fp32)
// ---------------------------------------------------------------------------
__global__ void init_acc(const int* __restrict__ users,
                         const int* __restrict__ items,
                         const float* __restrict__ ue,
                         const float* __restrict__ ie,
                         float4* __restrict__ uacc,
                         float4* __restrict__ iacc) {
    const int total = BATCH * (DIM / 4);
    int i = blockIdx.x * blockDim.x + threadIdx.x;
    if (i >= total) return;
    const int b = i >> 4;
    const int sub = i & 15;
    uacc[i] = reinterpret_cast<const float4*>(ue + (size_t)users[b] * DIM)[sub];
    iacc[i] = reinterpret_cast<const float4*>(ie + (size_t)items[b] * DIM)[sub];
}

// ---------------------------------------------------------------------------
// Pass 1: bucket histogram (LDS pre-aggregation)
// ---------------------------------------------------------------------------
__global__ __launch_bounds__(256) void bucket_hist(const int* __restrict__ rows,
                                                   int* __restrict__ bucket_cnt) {
    __shared__ int h[NBUCK];
    for (int i = threadIdx.x; i < NBUCK; i += 256) h[i] = 0;
    __syncthreads();
    const int s = blockIdx.x * HCHUNK;
    const int e = min(s + HCHUNK, NNZ);
    for (int i = s + threadIdx.x; i < e; i += 256)
        atomicAdd(&h[rows[i] >> BSHIFT], 1);
    __syncthreads();
    for (int i = threadIdx.x; i < NBUCK; i += 256)
        if (h[i]) atomicAdd(&bucket_cnt[i], h[i]);
}

// ---------------------------------------------------------------------------
// Pass 2: exclusive scan of 167 bucket counts (one block).
// raw base (bkt scatter) + slack-padded base (final CSR regions).
// ---------------------------------------------------------------------------
__global__ __launch_bounds__(256) void bucket_scan(const int* __restrict__ bucket_cnt,
                                                   int* __restrict__ bucket_base,
                                                   int* __restrict__ pad_base,
                                                   int* __restrict__ gcursor) {
    __shared__ int lds[256];
    const int t = threadIdx.x;
    const int v = (t < NBUCK) ? bucket_cnt[t] : 0;
    lds[t] = v;
    __syncthreads();
    int acc = v;
    for (int off = 1; off < 256; off <<= 1) {
        const int add = (t >= off) ? lds[t - off] : 0;
        __syncthreads();
        acc += add;
        lds[t] = acc;
        __syncthreads();
    }
    if (t < NBUCK) {
        const int ex = acc - v;
        bucket_base[t] = ex;
        gcursor[t] = ex;
        pad_base[t] = ex + t * PADSLACK;   // padded regions can grow by <= PADSLACK each
    }
    if (t == 0) bucket_base[NBUCK] = NNZ;
}

// ---------------------------------------------------------------------------
// Pass 3: scatter edges into bucket-major order; one 8B int2 per edge:
//   .x = (local_row << 18) | col,  .y = val bits
// ---------------------------------------------------------------------------
__global__ __launch_bounds__(256) void bucket_scatter(const int* __restrict__ rows,
                                                      const int* __restrict__ cols,
                                                      const float* __restrict__ vals,
                                                      int* __restrict__ gcursor,
                                                      int2* __restrict__ bkt) {
    __shared__ int h[NBUCK];
    __shared__ int base[NBUCK];
    for (int i = threadIdx.x; i < NBUCK; i += 256) h[i] = 0;
    __syncthreads();
    const int s = blockIdx.x * CHUNK;
    const int e = min(s + CHUNK, NNZ);
    for (int i = s + threadIdx.x; i < e; i += 256)
        atomicAdd(&h[rows[i] >> BSHIFT], 1);
    __syncthreads();
    for (int i = threadIdx.x; i < NBUCK; i += 256)
        base[i] = h[i] ? atomicAdd(&gcursor[i], h[i]) : 0;
    __syncthreads();
    for (int i = threadIdx.x; i < NBUCK; i += 256) h[i] = 0;
    __syncthreads();
    for (int i = s + threadIdx.x; i < e; i += 256) {
        const int r  = rows[i];
        const int bk = r >> BSHIFT;
        const int lr = r & (RPB - 1);
        const int pos = base[bk] + atomicAdd(&h[bk], 1);
        bkt[pos] = make_int2((lr << 18) | cols[i], __float_as_int(vals[i]));
    }
}

// ---------------------------------------------------------------------------
// Pass 4: per-bucket counting sort -> padded CSR (rows padded to 32-slot
// multiples; pad = byte-offset 0 / val 0 -> exact no-ops hitting x[0]'s line).
// Entry .x = col<<7 (byte offset). Also emits:
//   rowinfo[row]       = (padded_start << 8) | niter32   (for batch lookup)
//   sorted_row/sn[idx] = rows sorted by niter32 within each bucket (for the
//                        pair-row spmm: adjacent sorted rows have equal niter)
// ---------------------------------------------------------------------------
__global__ __launch_bounds__(512) void bucket_to_csr(const int* __restrict__ bucket_base,
                                                     const int* __restrict__ pad_base,
                                                     const int2* __restrict__ bkt,
                                                     unsigned* __restrict__ rowinfo,
                                                     int* __restrict__ sorted_row,
                                                     unsigned* __restrict__ sorted_sn,
                                                     int2* __restrict__ packed) {
    __shared__ int cnt[RPB];
    __shared__ int rs[RPB];
    __shared__ int st[RPB];
    __shared__ int tsum[512];
    __shared__ int nhist[16];
    __shared__ int nbase[16];
    const int k = blockIdx.x;
    const int rbase = k << BSHIFT;
    const int bs  = bucket_base[k];
    const int be  = bucket_base[k + 1];
    const int pbs = pad_base[k];
    const int nvalid = min(RPB, N_NODES - rbase);
    const int t = threadIdx.x;

    cnt[t] = 0; cnt[t + 512] = 0;
    if (t < 16) nhist[t] = 0;
    __syncthreads();
    for (int i = bs + t; i < be; i += 512)
        atomicAdd(&cnt[bkt[i].x >> 18], 1);
    __syncthreads();

    // padded lengths, exclusive scan (2 rows per thread + Hillis-Steele)
    const int v0 = cnt[2 * t];
    const int v1 = cnt[2 * t + 1];
    const int pl0 = (v0 + 31) & ~31;
    const int pl1 = (v1 + 31) & ~31;
    int acc = pl0 + pl1;
    tsum[t] = acc;
    __syncthreads();
    for (int off = 1; off < 512; off <<= 1) {
        const int add = (t >= off) ? tsum[t - off] : 0;
        __syncthreads();
        acc += add;
        tsum[t] = acc;
        __syncthreads();
    }
    const int excl = acc - (pl0 + pl1);
    const int s0 = pbs + excl;
    const int s1 = pbs + excl + pl0;
    rs[2 * t]     = excl;
    rs[2 * t + 1] = excl + pl0;
    st[2 * t]     = s0;
    st[2 * t + 1] = s1;
    const int ni0 = pl0 >> 5;
    const int ni1 = pl1 >> 5;
    if (2 * t < nvalid) {
        rowinfo[rbase + 2 * t] = ((unsigned)s0 << 8) | (unsigned)ni0;
        atomicAdd(&nhist[min(ni0, 15)], 1);
    }
    if (2 * t + 1 < nvalid) {
        rowinfo[rbase + 2 * t + 1] = ((unsigned)s1 << 8) | (unsigned)ni1;
        atomicAdd(&nhist[min(ni1, 15)], 1);
    }
    __syncthreads();
    if (t == 0) {
        int a = 0;
        #pragma unroll
        for (int j = 0; j < 16; ++j) { int c = nhist[j]; nbase[j] = a; nhist[j] = a; a += c; }
    }
    __syncthreads();
    if (2 * t < nvalid) {
        const int pos = atomicAdd(&nhist[min(ni0, 15)], 1);
        sorted_row[rbase + pos] = rbase + 2 * t;
        sorted_sn[rbase + pos]  = ((unsigned)s0 << 8) | (unsigned)ni0;
    }
    if (2 * t + 1 < nvalid) {
        const int pos = atomicAdd(&nhist[min(ni1, 15)], 1);
        sorted_row[rbase + pos] = rbase + 2 * t + 1;
        sorted_sn[rbase + pos]  = ((unsigned)s1 << 8) | (unsigned)ni1;
    }

    // fill this thread's two rows' pad slots
    for (int j = v0; j < pl0; ++j) packed[s0 + j] = make_int2(0, 0);
    for (int j = v1; j < pl1; ++j) packed[s1 + j] = make_int2(0, 0);
    __syncthreads();

    // scatter; atomicAdd on rs yields sequential positions within each row
    for (int i = bs + t; i < be; i += 512) {
        const int2 pk = bkt[i];
        const int lr = pk.x >> 18;
        const int pos = pbs + atomicAdd(&rs[lr], 1);
        packed[pos] = make_int2((pk.x & COLMASK) << 7, pk.y);
    }
}

// ---------------------------------------------------------------------------
// Pair-row SpMM gather core: each 32-lane half-wave owns one row; 4 edge
// groups x 8 slots = 32 slots (8 packed loads + 8 x-gathers in flight/iter).
// Rows padded to 32-slot multiples -> no masking. Entry .x = byte offset.
// ---------------------------------------------------------------------------
static __device__ __forceinline__ void spmm_row_accum32(
        const unsigned long long* __restrict__ packed,
        const unsigned short* __restrict__ x,
        int s, int e, int g, int d8b,
        f32x2& a0, f32x2& a1, f32x2& a2, f32x2& a3) {
    const char* xb = (const char*)x;
    for (int i = s; i < e; i += 32) {
        const int j = i + g;
        const unsigned long long p0 = __builtin_nontemporal_load(packed + j);
        const unsigned long long p1 = __builtin_nontemporal_load(packed + j + 4);
        const unsigned long long p2 = __builtin_nontemporal_load(packed + j + 8);
        const unsigned long long p3 = __builtin_nontemporal_load(packed + j + 12);
        const unsigned long long p4 = __builtin_nontemporal_load(packed + j + 16);
        const unsigned long long p5 = __builtin_nontemporal_load(packed + j + 20);
        const unsigned long long p6 = __builtin_nontemporal_load(packed + j + 24);
        const unsigned long long p7 = __builtin_nontemporal_load(packed + j + 28);
        const uint4 x0 = *reinterpret_cast<const uint4*>(xb + ((unsigned)(p0 & 0xFFFFFFFFu) + d8b));
        const uint4 x1 = *reinterpret_cast<const uint4*>(xb + ((unsigned)(p1 & 0xFFFFFFFFu) + d8b));
        const uint4 x2 = *reinterpret_cast<const uint4*>(xb + ((unsigned)(p2 & 0xFFFFFFFFu) + d8b));
        const uint4 x3 = *reinterpret_cast<const uint4*>(xb + ((unsigned)(p3 & 0xFFFFFFFFu) + d8b));
        const uint4 x4 = *reinterpret_cast<const uint4*>(xb + ((unsigned)(p4 & 0xFFFFFFFFu) + d8b));
        const uint4 x5 = *reinterpret_cast<const uint4*>(xb + ((unsigned)(p5 & 0xFFFFFFFFu) + d8b));
        const uint4 x6 = *reinterpret_cast<const uint4*>(xb + ((unsigned)(p6 & 0xFFFFFFFFu) + d8b));
        const uint4 x7 = *reinterpret_cast<const uint4*>(xb + ((unsigned)(p7 & 0xFFFFFFFFu) + d8b));
        const float v0 = __uint_as_float((unsigned)(p0 >> 32));
        const float v1 = __uint_as_float((unsigned)(p1 >> 32));
        const float v2 = __uint_as_float((unsigned)(p2 >> 32));
        const float v3 = __uint_as_float((unsigned)(p3 >> 32));
        const float v4 = __uint_as_float((unsigned)(p4 >> 32));
        const float v5 = __uint_as_float((unsigned)(p5 >> 32));
        const float v6 = __uint_as_float((unsigned)(p6 >> 32));
        const float v7 = __uint_as_float((unsigned)(p7 >> 32));
        const f32x2 w0 = {v0, v0}, w1 = {v1, v1}, w2 = {v2, v2}, w3 = {v3, v3};
        const f32x2 w4 = {v4, v4}, w5 = {v5, v5}, w6 = {v6, v6}, w7 = {v7, v7};
        a0 += w0 * (f32x2){bflo(x0.x), bfhi(x0.x)};
        a1 += w0 * (f32x2){bflo(x0.y), bfhi(x0.y)};
        a2 += w0 * (f32x2){bflo(x0.z), bfhi(x0.z)};
        a3 += w0 * (f32x2){bflo(x0.w), bfhi(x0.w)};
        a0 += w1 * (f32x2){bflo(x1.x), bfhi(x1.x)};
        a1 += w1 * (f32x2){bflo(x1.y), bfhi(x1.y)};
        a2 += w1 * (f32x2){bflo(x1.z), bfhi(x1.z)};
        a3 += w1 * (f32x2){bflo(x1.w), bfhi(x1.w)};
        a0 += w2 * (f32x2){bflo(x2.x), bfhi(x2.x)};
        a1 += w2 * (f32x2){bflo(x2.y), bfhi(x2.y)};
        a2 += w2 * (f32x2){bflo(x2.z), bfhi(x2.z)};
        a3 += w2 * (f32x2){bflo(x2.w), bfhi(x2.w)};
        a0 += w3 * (f32x2){bflo(x3.x), bfhi(x3.x)};
        a1 += w3 * (f32x2){bflo(x3.y), bfhi(x3.y)};
        a2 += w3 * (f32x2){bflo(x3.z), bfhi(x3.z)};
        a3 += w3 * (f32x2){bflo(x3.w), bfhi(x3.w)};
        a0 += w4 * (f32x2){bflo(x4.x), bfhi(x4.x)};
        a1 += w4 * (f32x2){bflo(x4.y), bfhi(x4.y)};
        a2 += w4 * (f32x2){bflo(x4.z), bfhi(x4.z)};
        a3 += w4 * (f32x2){bflo(x4.w), bfhi(x4.w)};
        a0 += w5 * (f32x2){bflo(x5.x), bfhi(x5.x)};
        a1 += w5 * (f32x2){bflo(x5.y), bfhi(x5.y)};
        a2 += w5 * (f32x2){bflo(x5.z), bfhi(x5.z)};
        a3 += w5 * (f32x2){bflo(x5.w), bfhi(x5.w)};
        a0 += w6 * (f32x2){bflo(x6.x), bfhi(x6.x)};
        a1 += w6 * (f32x2){bflo(x6.y), bfhi(x6.y)};
        a2 += w6 * (f32x2){bflo(x6.z), bfhi(x6.z)};
        a3 += w6 * (f32x2){bflo(x6.w), bfhi(x6.w)};
        a0 += w7 * (f32x2){bflo(x7.x), bfhi(x7.x)};
        a1 += w7 * (f32x2){bflo(x7.y), bfhi(x7.y)};
        a2 += w7 * (f32x2){bflo(x7.z), bfhi(x7.z)};
        a3 += w7 * (f32x2){bflo(x7.w), bfhi(x7.w)};
    }
}

static __device__ __forceinline__ void butterfly_half(f32x2& a0, f32x2& a1,
                                                      f32x2& a2, f32x2& a3) {
    #pragma unroll
    for (int off = 8; off < 32; off <<= 1) {   // 8, 16 — stays within 32-lane half
        a0.x += __shfl_xor(a0.x, off); a0.y += __shfl_xor(a0.y, off);
        a1.x += __shfl_xor(a1.x, off); a1.y += __shfl_xor(a1.y, off);
        a2.x += __shfl_xor(a2.x, off); a2.y += __shfl_xor(a2.y, off);
        a3.x += __shfl_xor(a3.x, off); a3.y += __shfl_xor(a3.y, off);
    }
}

// ---------------------------------------------------------------------------
// Full SpMM: one 32-lane half-wave per row, rows taken in degree-sorted order
// so the wave's two rows have (almost always) equal trip counts.
// ---------------------------------------------------------------------------
__global__ __launch_bounds__(256) void spmm_pair(const int* __restrict__ sorted_row,
                                                 const unsigned* __restrict__ sorted_sn,
                                                 const unsigned long long* __restrict__ packed,
                                                 const unsigned short* __restrict__ x,
                                                 unsigned short* __restrict__ y) {
    const int q    = blockIdx.x * 4 + (threadIdx.x >> 6);   // wave id
    const int half = (threadIdx.x >> 5) & 1;
    const int idx  = 2 * q + half;                          // < N_NODES (even)
    const int l32  = threadIdx.x & 31;
    const int g    = l32 >> 3;            // edge group 0..3
    const int d8b  = (l32 & 7) * 16;      // byte offset of this lane's 8 bf16 dims

    const int row = sorted_row[idx];
    const unsigned sn = sorted_sn[idx];
    const int s = (int)(sn >> 8);
    const int e = s + ((int)(sn & 0xFFu) << 5);

    f32x2 a0 = {0, 0}, a1 = {0, 0}, a2 = {0, 0}, a3 = {0, 0};
    spmm_row_accum32(packed, x, s, e, g, d8b, a0, a1, a2, a3);
    butterfly_half(a0, a1, a2, a3);

    if (l32 < 8) {
        uint4 o;
        o.x = f2bf(a0.x) | (f2bf(a0.y) << 16);
        o.y = f2bf(a1.x) | (f2bf(a1.y) << 16);
        o.z = f2bf(a2.x) | (f2bf(a2.y) << 16);
        o.w = f2bf(a3.x) | (f2bf(a3.y) << 16);
        *reinterpret_cast<uint4*>(y + (size_t)row * DIM + l32 * 8) = o;
    }
}

// ---------------------------------------------------------------------------
// Layer-3: only batch rows; half-wave per row, (user b, item b) paired.
// ---------------------------------------------------------------------------
__global__ __launch_bounds__(256) void spmm_batch_pair(const unsigned* __restrict__ rowinfo,
                                                       const unsigned long long* __restrict__ packed,
                                                       const unsigned short* __restrict__ x,
                                                       const int* __restrict__ users,
                                                       const int* __restrict__ items,
                                                       float* __restrict__ uacc,
                                                       float* __restrict__ iacc) {
    const int q    = blockIdx.x * 4 + (threadIdx.x >> 6);
    const int half = (threadIdx.x >> 5) & 1;
    const int idx  = 2 * q + half;                          // [0, 2*BATCH)
    const int l32  = threadIdx.x & 31;
    const int g    = l32 >> 3;
    const int d8b  = (l32 & 7) * 16;
    const int b = idx >> 1;
    const int isItem = idx & 1;
    const int row = isItem ? (NUM_USERS + items[b]) : users[b];
    const unsigned info = rowinfo[row];
    const int s = (int)(info >> 8);
    const int e = s + ((int)(info & 0xFFu) << 5);

    f32x2 a0 = {0, 0}, a1 = {0, 0}, a2 = {0, 0}, a3 = {0, 0};
    spmm_row_accum32(packed, x, s, e, g, d8b, a0, a1, a2, a3);
    butterfly_half(a0, a1, a2, a3);

    if (l32 < 8) {
        float* dst = (isItem ? iacc : uacc) + (size_t)b * DIM + l32 * 8;
        float4 q0 = reinterpret_cast<float4*>(dst)[0];
        float4 q1 = reinterpret_cast<float4*>(dst)[1];
        q0.x += a0.x; q0.y += a0.y; q0.z += a1.x; q0.w += a1.y;
        q1.x += a2.x; q1.y += a2.y; q1.z += a3.x; q1.w += a3.y;
        reinterpret_cast<float4*>(dst)[0] = q0;
        reinterpret_cast<float4*>(dst)[1] = q1;
    }
}

// ---------------------------------------------------------------------------
// uacc/iacc += y (bf16) at the batch rows (layers 1 and 2)
// ---------------------------------------------------------------------------
__global__ void gather_add(const int* __restrict__ users,
                           const int* __restrict__ items,
                           const unsigned short* __restrict__ y,
                           float4* __restrict__ uacc,
                           float4* __restrict__ iacc) {
    const int total = BATCH * (DIM / 4);
    int i = blockIdx.x * blockDim.x + threadIdx.x;
    if (i >= total) return;
    const int b = i >> 4;
    const int sub = i & 15;
    const int un = users[b];
    const int in = NUM_USERS + items[b];
    float4 a = uacc[i];
    const ushort4 yu = *reinterpret_cast<const ushort4*>(y + (size_t)un * DIM + sub * 4);
    a.x += bflo(yu.x); a.y += bflo(yu.y); a.z += bflo(yu.z); a.w += bflo(yu.w);
    uacc[i] = a;
    float4 c = iacc[i];
    const ushort4 yi = *reinterpret_cast<const ushort4*>(y + (size_t)in * DIM + sub * 4);
    c.x += bflo(yi.x); c.y += bflo(yi.y); c.z += bflo(yi.z); c.w += bflo(yi.w);
    iacc[i] = c;
}

// ---------------------------------------------------------------------------
// gamma[b] = dot(uacc[b], iacc[b]) / 16
// ---------------------------------------------------------------------------
__global__ void dot_out(const float* __restrict__ uacc,
                        const float* __restrict__ iacc,
                        float* __restrict__ gamma) {
    const int b = blockIdx.x * (blockDim.x / 64) + (threadIdx.x / 64);
    const int lane = threadIdx.x & 63;
    if (b >= BATCH) return;
    float p = uacc[b * DIM + lane] * iacc[b * DIM + lane];
    #pragma unroll
    for (int off = 32; off > 0; off >>= 1) p += __shfl_down(p, off);
    if (lane == 0) gamma[b] = p * 0.0625f;
}

// ---------------------------------------------------------------------------
extern "C" void kernel_launch(void* const* d_in, const int* in_sizes, int n_in,
                              void* d_out, int out_size, void* d_ws, size_t ws_size,
                              hipStream_t stream) {
    const float* ue    = (const float*)d_in[0];
    const float* ie    = (const float*)d_in[1];
    const float* oe    = (const float*)d_in[2];
    const float* vals  = (const float*)d_in[3];
    const int*   rows  = (const int*)d_in[4];
    const int*   cols  = (const int*)d_in[5];
    const int*   users = (const int*)d_in[6];
    const int*   items = (const int*)d_in[7];
    float* out = (float*)d_out;

    // ---- workspace layout ----
    // bucketed edges (40 MB) are dead after bucket_to_csr; cur (bf16, 21.8 MB)
    // is aliased on top (build_cur0 runs after pass 4).
    char* p = (char*)d_ws;
    int2* bkt = (int2*)p;                                      // 40 MB
    unsigned short* cur = (unsigned short*)p;                  // 21.76 MB (alias)
    p += (size_t)NNZ * sizeof(int2);
    unsigned short* nxt = (unsigned short*)p;                  // 21.76 MB
    p += (size_t)N_NODES * DIM * sizeof(unsigned short);
    int2* packed = (int2*)p;                                   // padded CSR, ~82.5 MB
    p += (size_t)(NNZ + (size_t)NBUCK * PADSLACK + 64) * sizeof(int2);
    unsigned* rowinfo    = (unsigned*)p;  p += (size_t)(N_NODES + 4) * sizeof(unsigned);
    int*      sorted_row = (int*)p;       p += (size_t)(N_NODES + 4) * sizeof(int);
    unsigned* sorted_sn  = (unsigned*)p;  p += (size_t)(N_NODES + 4) * sizeof(unsigned);
    int* bucket_cnt  = (int*)p;  p += (size_t)(NBUCK + 4) * sizeof(int);
    int* bucket_base = (int*)p;  p += (size_t)(NBUCK + 4) * sizeof(int);
    int* pad_base    = (int*)p;  p += (size_t)(NBUCK + 4) * sizeof(int);
    int* gcursor     = (int*)p;  p += (size_t)(NBUCK + 4) * sizeof(int);
    float* uacc = (float*)p;  p += (size_t)BATCH * DIM * sizeof(float);
    float* iacc = (float*)p;  p += (size_t)BATCH * DIM * sizeof(float);

    // ---- CSR build (bucketed, write-local, padded rows, degree-sorted) ----
    hipMemsetAsync(bucket_cnt, 0, (size_t)NBUCK * sizeof(int), stream);
    bucket_hist<<<HBLK, 256, 0, stream>>>(rows, bucket_cnt);
    bucket_scan<<<1, 256, 0, stream>>>(bucket_cnt, bucket_base, pad_base, gcursor);
    bucket_scatter<<<NBLK, 256, 0, stream>>>(rows, cols, vals, gcursor, bkt);
    bucket_to_csr<<<NBUCK, 512, 0, stream>>>(bucket_base, pad_base, bkt, rowinfo,
                                             sorted_row, sorted_sn, packed);

    // ---- node matrix (aliased over dead bucketed edges) + accumulator init ----
    build_cur0<<<2048, 256, 0, stream>>>(ue, ie, oe, (ushort4*)cur);
    init_acc<<<(BATCH * 16 + 255) / 256, 256, 0, stream>>>(users, items, ue, ie,
                                                           (float4*)uacc, (float4*)iacc);

    // ---- layers 1 and 2: full SpMM (pair-row), accumulate batch rows ----
    for (int layer = 0; layer < 2; ++layer) {
        spmm_pair<<<N_NODES / 8, 256, 0, stream>>>(sorted_row, sorted_sn,
                                                   (const unsigned long long*)packed,
                                                   cur, nxt);
        gather_add<<<(BATCH * 16 + 255) / 256, 256, 0, stream>>>(users, items, nxt,
                                                                 (float4*)uacc, (float4*)iacc);
        unsigned short* t = cur; cur = nxt; nxt = t;
    }

    // ---- layer 3: only the batch rows ----
    spmm_batch_pair<<<(2 * BATCH) / 8, 256, 0, stream>>>(rowinfo,
                                                         (const unsigned long long*)packed,
                                                         cur, users, items, uacc, iacc);

    // ---- output ----
    dot_out<<<BATCH / 4, 256, 0, stream>>>(uacc, iacc, out);
}

// Round 9
// 341.236 us; speedup vs baseline: 1.1794x; 1.1794x over previous
//
#include <hip/hip_runtime.h>

#define NUM_USERS 100000
#define NUM_ITEMS 50000
#define NUM_OTHERS 20000
#define N_NODES 170000   // NUM_USERS + NUM_ITEMS + NUM_OTHERS
#define DIM 64
#define NNZ 5000000
#define BATCH 8192

#define BSHIFT 10
#define RPB (1 << BSHIFT)                       // 1024 rows per bucket
#define NBUCK ((N_NODES + RPB - 1) / RPB)       // 167 buckets
#define COLMASK 0x3FFFF                         // 18 bits for col (N_NODES < 2^18)
#define BCAPSHIFT 15
#define BCAP (1 << BCAPSHIFT)                   // 32768 slots per bucket (mean 29940, +16 sigma)
#define NBLK 512                                // blocks for scatter pass
#define CHUNK ((NNZ + NBLK - 1) / NBLK)         // 9766 edges per block

typedef float f32x2 __attribute__((ext_vector_type(2)));

// fp32 -> bf16 round-to-nearest-even
static __device__ __forceinline__ unsigned f2bf(float f) {
    unsigned u = __float_as_uint(f);
    u = (u + 0x7fff + ((u >> 16) & 1)) >> 16;
    return u;
}
static __device__ __forceinline__ float bflo(unsigned u) {   // low ushort -> f32
    return __uint_as_float(u << 16);
}
static __device__ __forceinline__ float bfhi(unsigned u) {   // high ushort -> f32
    return __uint_as_float(u & 0xFFFF0000u);
}

// ---------------------------------------------------------------------------
// cur0 = concat(user_emb, item_emb, other_emb)  -> bf16
// ---------------------------------------------------------------------------
__global__ void build_cur0(const float* __restrict__ ue,
                           const float* __restrict__ ie,
                           const float* __restrict__ oe,
                           ushort4* __restrict__ cur) {
    const int total = N_NODES * (DIM / 4);
    for (int i = blockIdx.x * blockDim.x + threadIdx.x; i < total;
         i += gridDim.x * blockDim.x) {
        const int node = i >> 4;
        const int sub  = i & 15;
        const float* src;
        if (node < NUM_USERS)                  src = ue + (size_t)node * DIM;
        else if (node < NUM_USERS + NUM_ITEMS) src = ie + (size_t)(node - NUM_USERS) * DIM;
        else                                   src = oe + (size_t)(node - NUM_USERS - NUM_ITEMS) * DIM;
        const float4 f = reinterpret_cast<const float4*>(src)[sub];
        ushort4 o;
        o.x = (unsigned short)f2bf(f.x); o.y = (unsigned short)f2bf(f.y);
        o.z = (unsigned short)f2bf(f.z); o.w = (unsigned short)f2bf(f.w);
        cur[i] = o;
    }
}

// ---------------------------------------------------------------------------
// batch accumulators start as layer-0 embeddings (fp32)
// ---------------------------------------------------------------------------
__global__ void init_acc(const int* __restrict__ users,
                         const int* __restrict__ items,
                         const float* __restrict__ ue,
                         const float* __restrict__ ie,
                         float4* __restrict__ uacc,
                         float4* __restrict__ iacc) {
    const int total = BATCH * (DIM / 4);
    int i = blockIdx.x * blockDim.x + threadIdx.x;
    if (i >= total) return;
    const int b = i >> 4;
    const int sub = i & 15;
    uacc[i] = reinterpret_cast<const float4*>(ue + (size_t)users[b] * DIM)[sub];
    iacc[i] = reinterpret_cast<const float4*>(ie + (size_t)items[b] * DIM)[sub];
}

// ---------------------------------------------------------------------------
// Pass 1 (single scatter pass, no global histogram / scan):
// each block builds an LDS bucket histogram of its chunk, reserves contiguous
// ranges in each bucket's FIXED-CAPACITY region via one atomic per touched
// bucket, then appends. Entry: .x = (local_row << 18) | col, .y = val bits.
// ---------------------------------------------------------------------------
__global__ __launch_bounds__(256) void bucket_scatter(const int* __restrict__ rows,
                                                      const int* __restrict__ cols,
                                                      const float* __restrict__ vals,
                                                      int* __restrict__ bucket_cnt,
                                                      int2* __restrict__ bkt) {
    __shared__ int h[NBUCK];
    __shared__ int base[NBUCK];
    for (int i = threadIdx.x; i < NBUCK; i += 256) h[i] = 0;
    __syncthreads();
    const int s = blockIdx.x * CHUNK;
    const int e = min(s + CHUNK, NNZ);
    for (int i = s + threadIdx.x; i < e; i += 256)
        atomicAdd(&h[rows[i] >> BSHIFT], 1);
    __syncthreads();
    for (int i = threadIdx.x; i < NBUCK; i += 256)
        base[i] = h[i] ? atomicAdd(&bucket_cnt[i], h[i]) : 0;
    __syncthreads();
    for (int i = threadIdx.x; i < NBUCK; i += 256) h[i] = 0;
    __syncthreads();
    for (int i = s + threadIdx.x; i < e; i += 256) {
        const int r  = rows[i];
        const int bk = r >> BSHIFT;
        const int lr = r & (RPB - 1);
        const int pos = base[bk] + atomicAdd(&h[bk], 1);
        bkt[((size_t)bk << BCAPSHIFT) + pos] = make_int2((lr << 18) | cols[i],
                                                         __float_as_int(vals[i]));
    }
}

// ---------------------------------------------------------------------------
// Pass 2: per-bucket counting sort -> final CSR inside the bucket's fixed
// region (no global prefix needed). Entry .x = col<<7 (byte offset into the
// bf16 node matrix). rowinfo[row] = (abs_start << 8) | exact_len  (len < 256).
// ---------------------------------------------------------------------------
__global__ __launch_bounds__(512) void bucket_to_csr(const int* __restrict__ bucket_cnt,
                                                     const int2* __restrict__ bkt,
                                                     unsigned* __restrict__ rowinfo,
                                                     int2* __restrict__ packed) {
    __shared__ int cnt[RPB];
    __shared__ int rs[RPB];
    __shared__ int tsum[512];
    const int k = blockIdx.x;
    const int rbase = k << BSHIFT;
    const int nvalid = min(RPB, N_NODES - rbase);
    const int n = bucket_cnt[k];
    const int2* __restrict__ src = bkt + ((size_t)k << BCAPSHIFT);
    int2* __restrict__ dst = packed + ((size_t)k << BCAPSHIFT);
    const int t = threadIdx.x;

    cnt[t] = 0; cnt[t + 512] = 0;
    __syncthreads();
    for (int i = t; i < n; i += 512)
        atomicAdd(&cnt[src[i].x >> 18], 1);
    __syncthreads();

    // exact lengths, exclusive scan (2 rows per thread + Hillis-Steele)
    const int v0 = cnt[2 * t];
    const int v1 = cnt[2 * t + 1];
    int acc = v0 + v1;
    tsum[t] = acc;
    __syncthreads();
    for (int off = 1; off < 512; off <<= 1) {
        const int add = (t >= off) ? tsum[t - off] : 0;
        __syncthreads();
        acc += add;
        tsum[t] = acc;
        __syncthreads();
    }
    const int excl = acc - (v0 + v1);
    rs[2 * t]     = excl;
    rs[2 * t + 1] = excl + v0;
    const unsigned abs0 = (unsigned)((k << BCAPSHIFT) + excl);
    if (2 * t < nvalid)
        rowinfo[rbase + 2 * t]     = (abs0 << 8) | (unsigned)v0;
    if (2 * t + 1 < nvalid)
        rowinfo[rbase + 2 * t + 1] = ((abs0 + (unsigned)v0) << 8) | (unsigned)v1;
    __syncthreads();

    // scatter; atomicAdd on rs yields sequential positions within each row
    for (int i = t; i < n; i += 512) {
        const int2 pk = src[i];
        const int lr = pk.x >> 18;
        const int pos = atomicAdd(&rs[lr], 1);
        dst[pos] = make_int2((pk.x & COLMASK) << 7, pk.y);
    }
}

// ---------------------------------------------------------------------------
// SpMM gather core (best-known round-6 shape): 32 edge-slots per iteration,
// 8 lanes per edge (16B/lane); masked tail slots clamp to byte-offset 0
// (x[0]'s L1-resident line, ~free). Entry .x is the byte offset col*128.
// ---------------------------------------------------------------------------
static __device__ __forceinline__ void spmm_row_accum(
        const unsigned long long* __restrict__ packed,
        const unsigned short* __restrict__ x,
        int s, int e, int g, int d8b,
        f32x2& a0, f32x2& a1, f32x2& a2, f32x2& a3) {
    const char* xb = (const char*)x;
    for (int i = s; i < e; i += 32) {
        const int j0 = i + g;
        const int j1 = j0 + 8;
        const int j2 = j0 + 16;
        const int j3 = j0 + 24;
        const unsigned long long p0 = __builtin_nontemporal_load(packed + j0);
        const unsigned long long p1 = __builtin_nontemporal_load(packed + j1);
        const unsigned long long p2 = __builtin_nontemporal_load(packed + j2);
        const unsigned long long p3 = __builtin_nontemporal_load(packed + j3);
        const unsigned c0 = ((j0 < e) ? (unsigned)(p0 & 0xFFFFFFFFu) : 0u) + d8b;
        const unsigned c1 = ((j1 < e) ? (unsigned)(p1 & 0xFFFFFFFFu) : 0u) + d8b;
        const unsigned c2 = ((j2 < e) ? (unsigned)(p2 & 0xFFFFFFFFu) : 0u) + d8b;
        const unsigned c3 = ((j3 < e) ? (unsigned)(p3 & 0xFFFFFFFFu) : 0u) + d8b;
        const float v0 = (j0 < e) ? __uint_as_float((unsigned)(p0 >> 32)) : 0.f;
        const float v1 = (j1 < e) ? __uint_as_float((unsigned)(p1 >> 32)) : 0.f;
        const float v2 = (j2 < e) ? __uint_as_float((unsigned)(p2 >> 32)) : 0.f;
        const float v3 = (j3 < e) ? __uint_as_float((unsigned)(p3 >> 32)) : 0.f;
        const uint4 x0 = *reinterpret_cast<const uint4*>(xb + c0);
        const uint4 x1 = *reinterpret_cast<const uint4*>(xb + c1);
        const uint4 x2 = *reinterpret_cast<const uint4*>(xb + c2);
        const uint4 x3 = *reinterpret_cast<const uint4*>(xb + c3);
        const f32x2 w0 = {v0, v0}, w1 = {v1, v1}, w2 = {v2, v2}, w3 = {v3, v3};
        a0 += w0 * (f32x2){bflo(x0.x), bfhi(x0.x)};
        a1 += w0 * (f32x2){bflo(x0.y), bfhi(x0.y)};
        a2 += w0 * (f32x2){bflo(x0.z), bfhi(x0.z)};
        a3 += w0 * (f32x2){bflo(x0.w), bfhi(x0.w)};
        a0 += w1 * (f32x2){bflo(x1.x), bfhi(x1.x)};
        a1 += w1 * (f32x2){bflo(x1.y), bfhi(x1.y)};
        a2 += w1 * (f32x2){bflo(x1.z), bfhi(x1.z)};
        a3 += w1 * (f32x2){bflo(x1.w), bfhi(x1.w)};
        a0 += w2 * (f32x2){bflo(x2.x), bfhi(x2.x)};
        a1 += w2 * (f32x2){bflo(x2.y), bfhi(x2.y)};
        a2 += w2 * (f32x2){bflo(x2.z), bfhi(x2.z)};
        a3 += w2 * (f32x2){bflo(x2.w), bfhi(x2.w)};
        a0 += w3 * (f32x2){bflo(x3.x), bfhi(x3.x)};
        a1 += w3 * (f32x2){bflo(x3.y), bfhi(x3.y)};
        a2 += w3 * (f32x2){bflo(x3.z), bfhi(x3.z)};
        a3 += w3 * (f32x2){bflo(x3.w), bfhi(x3.w)};
    }
}

static __device__ __forceinline__ void butterfly8(f32x2& a0, f32x2& a1,
                                                  f32x2& a2, f32x2& a3) {
    #pragma unroll
    for (int off = 8; off < 64; off <<= 1) {
        a0.x += __shfl_xor(a0.x, off); a0.y += __shfl_xor(a0.y, off);
        a1.x += __shfl_xor(a1.x, off); a1.y += __shfl_xor(a1.y, off);
        a2.x += __shfl_xor(a2.x, off); a2.y += __shfl_xor(a2.y, off);
        a3.x += __shfl_xor(a3.x, off); a3.y += __shfl_xor(a3.y, off);
    }
}

// ---------------------------------------------------------------------------
// Full SpMM: one wave per row
// ---------------------------------------------------------------------------
__global__ __launch_bounds__(256) void spmm_csr8(const unsigned* __restrict__ rowinfo,
                                                 const unsigned long long* __restrict__ packed,
                                                 const unsigned short* __restrict__ x,
                                                 unsigned short* __restrict__ y) {
    const int row  = blockIdx.x * 4 + (threadIdx.x >> 6);
    const int lane = threadIdx.x & 63;
    if (row >= N_NODES) return;
    const unsigned info = rowinfo[row];
    const int s = (int)(info >> 8);
    const int e = s + (int)(info & 0xFFu);
    const int g   = lane >> 3;            // edge group 0..7
    const int d8b = (lane & 7) * 16;      // byte offset of this lane's 8 bf16 dims

    f32x2 a0 = {0, 0}, a1 = {0, 0}, a2 = {0, 0}, a3 = {0, 0};
    spmm_row_accum(packed, x, s, e, g, d8b, a0, a1, a2, a3);
    butterfly8(a0, a1, a2, a3);

    if (lane < 8) {
        uint4 o;
        o.x = f2bf(a0.x) | (f2bf(a0.y) << 16);
        o.y = f2bf(a1.x) | (f2bf(a1.y) << 16);
        o.z = f2bf(a2.x) | (f2bf(a2.y) << 16);
        o.w = f2bf(a3.x) | (f2bf(a3.y) << 16);
        *reinterpret_cast<uint4*>(y + (size_t)row * DIM + lane * 8) = o;
    }
}

// ---------------------------------------------------------------------------
// Layer-3: only batch rows, accumulate into fp32 uacc/iacc
// ---------------------------------------------------------------------------
__global__ __launch_bounds__(256) void spmm_batch_final8(const unsigned* __restrict__ rowinfo,
                                                         const unsigned long long* __restrict__ packed,
                                                         const unsigned short* __restrict__ x,
                                                         const int* __restrict__ users,
                                                         const int* __restrict__ items,
                                                         float* __restrict__ uacc,
                                                         float* __restrict__ iacc) {
    const int w    = blockIdx.x * 4 + (threadIdx.x >> 6);   // [0, 2*BATCH)
    const int lane = threadIdx.x & 63;
    if (w >= 2 * BATCH) return;
    const int b = w >> 1;
    const int isItem = w & 1;
    const int row = isItem ? (NUM_USERS + items[b]) : users[b];
    const unsigned info = rowinfo[row];
    const int s = (int)(info >> 8);
    const int e = s + (int)(info & 0xFFu);
    const int g   = lane >> 3;
    const int d8b = (lane & 7) * 16;

    f32x2 a0 = {0, 0}, a1 = {0, 0}, a2 = {0, 0}, a3 = {0, 0};
    spmm_row_accum(packed, x, s, e, g, d8b, a0, a1, a2, a3);
    butterfly8(a0, a1, a2, a3);

    if (lane < 8) {
        float* dst = (isItem ? iacc : uacc) + (size_t)b * DIM + lane * 8;
        float4 q0 = reinterpret_cast<float4*>(dst)[0];
        float4 q1 = reinterpret_cast<float4*>(dst)[1];
        q0.x += a0.x; q0.y += a0.y; q0.z += a1.x; q0.w += a1.y;
        q1.x += a2.x; q1.y += a2.y; q1.z += a3.x; q1.w += a3.y;
        reinterpret_cast<float4*>(dst)[0] = q0;
        reinterpret_cast<float4*>(dst)[1] = q1;
    }
}

// ---------------------------------------------------------------------------
// uacc/iacc += y (bf16) at the batch rows (layers 1 and 2)
// ---------------------------------------------------------------------------
__global__ void gather_add(const int* __restrict__ users,
                           const int* __restrict__ items,
                           const unsigned short* __restrict__ y,
                           float4* __restrict__ uacc,
                           float4* __restrict__ iacc) {
    const int total = BATCH * (DIM / 4);
    int i = blockIdx.x * blockDim.x + threadIdx.x;
    if (i >= total) return;
    const int b = i >> 4;
    const int sub = i & 15;
    const int un = users[b];
    const int in = NUM_USERS + items[b];
    float4 a = uacc[i];
    const ushort4 yu = *reinterpret_cast<const ushort4*>(y + (size_t)un * DIM + sub * 4);
    a.x += bflo(yu.x); a.y += bflo(yu.y); a.z += bflo(yu.z); a.w += bflo(yu.w);
    uacc[i] = a;
    float4 c = iacc[i];
    const ushort4 yi = *reinterpret_cast<const ushort4*>(y + (size_t)in * DIM + sub * 4);
    c.x += bflo(yi.x); c.y += bflo(yi.y); c.z += bflo(yi.z); c.w += bflo(yi.w);
    iacc[i] = c;
}

// ---------------------------------------------------------------------------
// gamma[b] = dot(uacc[b], iacc[b]) / 16
// ---------------------------------------------------------------------------
__global__ void dot_out(const float* __restrict__ uacc,
                        const float* __restrict__ iacc,
                        float* __restrict__ gamma) {
    const int b = blockIdx.x * (blockDim.x / 64) + (threadIdx.x / 64);
    const int lane = threadIdx.x & 63;
    if (b >= BATCH) return;
    float p = uacc[b * DIM + lane] * iacc[b * DIM + lane];
    #pragma unroll
    for (int off = 32; off > 0; off >>= 1) p += __shfl_down(p, off);
    if (lane == 0) gamma[b] = p * 0.0625f;
}

// ---------------------------------------------------------------------------
extern "C" void kernel_launch(void* const* d_in, const int* in_sizes, int n_in,
                              void* d_out, int out_size, void* d_ws, size_t ws_size,
                              hipStream_t stream) {
    const float* ue    = (const float*)d_in[0];
    const float* ie    = (const float*)d_in[1];
    const float* oe    = (const float*)d_in[2];
    const float* vals  = (const float*)d_in[3];
    const int*   rows  = (const int*)d_in[4];
    const int*   cols  = (const int*)d_in[5];
    const int*   users = (const int*)d_in[6];
    const int*   items = (const int*)d_in[7];
    float* out = (float*)d_out;

    // ---- workspace layout ----
    // bkt (43.8 MB) is dead after bucket_to_csr; cur (bf16, 21.8 MB) is
    // aliased on top (build_cur0 runs after pass 2).
    char* p = (char*)d_ws;
    int2* bkt = (int2*)p;                                      // 43.8 MB
    unsigned short* cur = (unsigned short*)p;                  // 21.76 MB (alias)
    p += ((size_t)NBUCK << BCAPSHIFT) * sizeof(int2);
    unsigned short* nxt = (unsigned short*)p;                  // 21.76 MB
    p += (size_t)N_NODES * DIM * sizeof(unsigned short);
    int2* packed = (int2*)p;                                   // 43.8 MB + tail pad
    p += (((size_t)NBUCK << BCAPSHIFT) + 64) * sizeof(int2);
    unsigned* rowinfo = (unsigned*)p;  p += (size_t)(N_NODES + 4) * sizeof(unsigned);
    int* bucket_cnt = (int*)p;  p += (size_t)(NBUCK + 4) * sizeof(int);
    float* uacc = (float*)p;  p += (size_t)BATCH * DIM * sizeof(float);
    float* iacc = (float*)p;  p += (size_t)BATCH * DIM * sizeof(float);

    // ---- CSR build: 2 passes, fixed-capacity buckets, no histogram/scan ----
    hipMemsetAsync(bucket_cnt, 0, (size_t)NBUCK * sizeof(int), stream);
    bucket_scatter<<<NBLK, 256, 0, stream>>>(rows, cols, vals, bucket_cnt, bkt);
    bucket_to_csr<<<NBUCK, 512, 0, stream>>>(bucket_cnt, bkt, rowinfo, packed);

    // ---- node matrix (aliased over dead bkt) + accumulator init ----
    build_cur0<<<2048, 256, 0, stream>>>(ue, ie, oe, (ushort4*)cur);
    init_acc<<<(BATCH * 16 + 255) / 256, 256, 0, stream>>>(users, items, ue, ie,
                                                           (float4*)uacc, (float4*)iacc);

    // ---- layers 1 and 2: full SpMM, accumulate batch rows ----
    for (int layer = 0; layer < 2; ++layer) {
        spmm_csr8<<<(N_NODES + 3) / 4, 256, 0, stream>>>(rowinfo,
                                                         (const unsigned long long*)packed,
                                                         cur, nxt);
        gather_add<<<(BATCH * 16 + 255) / 256, 256, 0, stream>>>(users, items, nxt,
                                                                 (float4*)uacc, (float4*)iacc);
        unsigned short* t = cur; cur = nxt; nxt = t;
    }

    // ---- layer 3: only the batch rows ----
    spmm_batch_final8<<<(2 * BATCH) / 4 + 1, 256, 0, stream>>>(rowinfo,
                                                               (const unsigned long long*)packed,
                                                               cur, users, items, uacc, iacc);

    // ---- output ----
    dot_out<<<BATCH / 4, 256, 0, stream>>>(uacc, iacc, out);
}